// Round 1
// baseline (508.144 us; speedup 1.0000x reference)
//
#include <hip/hip_runtime.h>
#include <math.h>

// Deformable conv fwd: B=4, C=CO=64, H=W=128, K=3, pad=1, stride=1.
// ws layout (floats): [0, 4194304) = x transposed to NHWC (16 MiB)
//                     [4194304, 5373952) = offset field [B][18][H][W] (4.5 MiB)
// requires ws_size >= ~20.5 MiB.

namespace {
constexpr int Bn = 4, Cn = 64, Hn = 128, Wn = 128, COn = 64;
constexpr int HWn = Hn * Wn;            // 16384
constexpr int CKn = Cn * 9;             // 576
constexpr int SROW = 580;               // padded LDS row stride (floats); 580 = 4*145 (odd) -> 2-way max
constexpr int TILE = 16;                // pixels per block in main kernel
constexpr size_t XT_OFF = 0;
constexpr size_t OFF_OFF = (size_t)Bn * HWn * Cn;  // 4194304 floats
}

// ---- Kernel 1: NCHW -> NHWC transpose of x ----
__global__ __launch_bounds__(256) void k_transpose(const float* __restrict__ x,
                                                   float* __restrict__ xt) {
    __shared__ float tile[64][65];
    const int tid  = threadIdx.x;
    const int lane = tid & 63;
    const int grp  = tid >> 6;
    const int b    = blockIdx.x >> 8;          // 256 hw-tiles per batch
    const int hw0  = (blockIdx.x & 255) << 6;  // 64 pixels per tile
#pragma unroll
    for (int r = 0; r < 16; ++r) {
        const int c = (r << 2) + grp;
        tile[c][lane] = x[(b * Cn + c) * HWn + hw0 + lane];   // coalesced read
    }
    __syncthreads();
#pragma unroll
    for (int r = 0; r < 16; ++r) {
        const int hwl = (r << 2) + grp;
        xt[(size_t)(b * HWn + hw0 + hwl) * Cn + lane] = tile[lane][hwl];  // coalesced write
    }
}

// ---- Kernel 2: 18-channel 3x3 offset conv (NCHW direct) ----
__global__ __launch_bounds__(256) void k_offset_conv(const float* __restrict__ x,
                                                     const float* __restrict__ w_off,
                                                     const float* __restrict__ b_off,
                                                     float* __restrict__ off) {
    const int idx = blockIdx.x * 256 + threadIdx.x;  // [b][ch][y][x], x fastest
    const int xx = idx & (Wn - 1);
    const int yy = (idx >> 7) & (Hn - 1);
    const int ch = (idx >> 14) % 18;
    const int b  = idx / (18 * HWn);
    float acc = b_off[ch];
    const float* xb = x + (size_t)b * Cn * HWn;
    const float* wb = w_off + ch * CKn;
#pragma unroll
    for (int ky = 0; ky < 3; ++ky) {
        const int sy = yy + ky - 1;
        if (sy < 0 || sy >= Hn) continue;
#pragma unroll
        for (int kx = 0; kx < 3; ++kx) {
            const int sx = xx + kx - 1;
            if (sx < 0 || sx >= Wn) continue;
            const float* xp = xb + sy * Wn + sx;
            const float* wq = wb + ky * 3 + kx;
#pragma unroll 8
            for (int c = 0; c < Cn; ++c)
                acc = fmaf(xp[c * HWn], wq[c * 9], acc);  // x read coalesced across lanes
        }
    }
    off[idx] = acc;
}

// ---- Kernel 3: bilinear gather (phase 1) + 64x576 contraction (phase 2) ----
__global__ __launch_bounds__(256) void k_deform(const float* __restrict__ xt,
                                                const float* __restrict__ off,
                                                const float* __restrict__ w_def,
                                                float* __restrict__ out) {
    __shared__ float smem[TILE * SROW];  // sampled[pix][c*9+k], padded rows
    const int tid  = threadIdx.x;
    const int lane = tid & 63;
    const int wid  = tid >> 6;
    const int b    = blockIdx.x >> 10;           // 1024 tiles per batch
    const int p0   = (blockIdx.x & 1023) * TILE; // 16 consecutive pixels (same row)

    // Phase 1: lane = input channel; each wave gathers 4 pixels
    const float* xtb = xt + (size_t)(b * HWn) * Cn + lane;
    for (int pg = 0; pg < 4; ++pg) {
        const int pix = (wid << 2) + pg;
        const int p   = p0 + pix;
        const int oy  = p >> 7;
        const int ox  = p & (Wn - 1);
        const float* offp = off + (size_t)(b * 18) * HWn + p;
#pragma unroll
        for (int k = 0; k < 9; ++k) {
            const float dyo = offp[(2 * k) * HWn];       // broadcast load
            const float dxo = offp[(2 * k + 1) * HWn];
            const float py = dyo + (float)(oy + k / 3 - 1);
            const float px = dxo + (float)(ox + k % 3 - 1);
            const float fy = floorf(py);
            const float fx = floorf(px);
            const float ay = py - fy;
            const float ax = px - fx;
            const int iy0 = (int)fy;
            const int ix0 = (int)fx;
            const float w00 = (1.f - ay) * (1.f - ax);
            const float w01 = (1.f - ay) * ax;
            const float w10 = ay * (1.f - ax);
            const float w11 = ay * ax;
            float v = 0.f;
            const bool x0ok = (ix0 >= 0) & (ix0 < Wn);
            const bool x1ok = (ix0 + 1 >= 0) & (ix0 + 1 < Wn);
            if (iy0 >= 0 && iy0 < Hn) {
                const float* row = xtb + (size_t)(iy0 * Wn) * Cn;
                if (x0ok) v = fmaf(w00, row[ix0 * Cn], v);        // coalesced 256B gather
                if (x1ok) v = fmaf(w01, row[(ix0 + 1) * Cn], v);
            }
            if (iy0 + 1 >= 0 && iy0 + 1 < Hn) {
                const float* row = xtb + (size_t)((iy0 + 1) * Wn) * Cn;
                if (x0ok) v = fmaf(w10, row[ix0 * Cn], v);
                if (x1ok) v = fmaf(w11, row[(ix0 + 1) * Cn], v);
            }
            smem[pix * SROW + lane * 9 + k] = v;  // stride 9: 2-way max, free
        }
    }
    __syncthreads();

    // Phase 2: thread = (pixel pl, 4 output channels); wave covers a 16-row
    // quarter of w_def -> each block reads w_def exactly once (147 KB).
    const int pl = lane & 15;
    const int og = lane >> 4;
    const int ob = (wid << 4) + (og << 2);
    float acc0 = 0.f, acc1 = 0.f, acc2 = 0.f, acc3 = 0.f;
    const float* sp = smem + pl * SROW;
    const float* w0 = w_def + (size_t)(ob + 0) * CKn;
    const float* w1 = w_def + (size_t)(ob + 1) * CKn;
    const float* w2 = w_def + (size_t)(ob + 2) * CKn;
    const float* w3 = w_def + (size_t)(ob + 3) * CKn;
#pragma unroll 4
    for (int q = 0; q < CKn; q += 4) {
        const float4 s = *reinterpret_cast<const float4*>(sp + q);  // 2-way bcast, free
        float4 a;
        a = *reinterpret_cast<const float4*>(w0 + q);
        acc0 = fmaf(a.x, s.x, fmaf(a.y, s.y, fmaf(a.z, s.z, fmaf(a.w, s.w, acc0))));
        a = *reinterpret_cast<const float4*>(w1 + q);
        acc1 = fmaf(a.x, s.x, fmaf(a.y, s.y, fmaf(a.z, s.z, fmaf(a.w, s.w, acc1))));
        a = *reinterpret_cast<const float4*>(w2 + q);
        acc2 = fmaf(a.x, s.x, fmaf(a.y, s.y, fmaf(a.z, s.z, fmaf(a.w, s.w, acc2))));
        a = *reinterpret_cast<const float4*>(w3 + q);
        acc3 = fmaf(a.x, s.x, fmaf(a.y, s.y, fmaf(a.z, s.z, fmaf(a.w, s.w, acc3))));
    }
    const int p = p0 + pl;
    float* op = out + (size_t)(b * COn + ob) * HWn + p;
    op[0 * HWn] = acc0;
    op[1 * HWn] = acc1;
    op[2 * HWn] = acc2;
    op[3 * HWn] = acc3;
}

extern "C" void kernel_launch(void* const* d_in, const int* in_sizes, int n_in,
                              void* d_out, int out_size, void* d_ws, size_t ws_size,
                              hipStream_t stream) {
    const float* x     = (const float*)d_in[0];
    const float* w_off = (const float*)d_in[1];
    const float* b_off = (const float*)d_in[2];
    const float* w_def = (const float*)d_in[3];
    float* outp = (float*)d_out;
    float* wsf  = (float*)d_ws;
    float* xt   = wsf + XT_OFF;
    float* off  = wsf + OFF_OFF;

    // K1: NCHW -> NHWC (1024 blocks)
    k_transpose<<<Bn * 256, 256, 0, stream>>>(x, xt);
    // K2: offset conv (4*18*16384 threads)
    k_offset_conv<<<(Bn * 18 * HWn) / 256, 256, 0, stream>>>(x, w_off, b_off, off);
    // K3: main deformable conv (4096 blocks x 16 pixels)
    k_deform<<<Bn * (HWn / TILE), 256, 0, stream>>>(xt, off, w_def, outp);
}

// Round 2
// 302.647 us; speedup vs baseline: 1.6790x; 1.6790x over previous
//
#include <hip/hip_runtime.h>
#include <math.h>

// Deformable conv fwd: B=4, C=CO=64, H=W=128, K=3, pad=1, stride=1.
// ws layout (float units):
//   [0, 4194304)              xt: x transposed to NHWC (16 MiB)
//   [4194304, 4212736)        aswz: w_def as bf16 in MFMA A-frag layout (72 KiB)
//   [4212736, 5392384)        off: offset field [B][18][H][W] (4.5 MiB)

typedef short  v4s __attribute__((ext_vector_type(4)));
typedef short  v8s __attribute__((ext_vector_type(8)));
typedef float  v4f __attribute__((ext_vector_type(4)));

namespace {
constexpr int Bn = 4, Cn = 64, Hn = 128, Wn = 128, COn = 64;
constexpr int HWn = Hn * Wn;            // 16384
constexpr int CKn = Cn * 9;             // 576
constexpr int TILE = 32;                // pixels per block in main kernel
constexpr int RS = 580;                 // LDS row stride in bf16 elems (1160 B = 290 dw ≡ 2 mod 32)
constexpr size_t XT_OFF  = 0;
constexpr size_t ASWZ_OFF = (size_t)Bn * HWn * Cn;        // 4194304 floats
constexpr size_t OFF_OFF  = ASWZ_OFF + 18432;             // + 73728 B of bf16
}

__device__ __forceinline__ unsigned short f2bf(float f) {
    union { float f; unsigned int u; } v; v.f = f;
    unsigned int u = v.u;
    u += 0x7fffu + ((u >> 16) & 1u);    // round-to-nearest-even
    return (unsigned short)(u >> 16);
}

// ---- Kernel 1: NCHW -> NHWC transpose of x ----
__global__ __launch_bounds__(256) void k_transpose(const float* __restrict__ x,
                                                   float* __restrict__ xt) {
    __shared__ float tile[64][65];
    const int tid  = threadIdx.x;
    const int lane = tid & 63;
    const int grp  = tid >> 6;
    const int b    = blockIdx.x >> 8;
    const int hw0  = (blockIdx.x & 255) << 6;
#pragma unroll
    for (int r = 0; r < 16; ++r) {
        const int c = (r << 2) + grp;
        tile[c][lane] = x[(b * Cn + c) * HWn + hw0 + lane];
    }
    __syncthreads();
#pragma unroll
    for (int r = 0; r < 16; ++r) {
        const int hwl = (r << 2) + grp;
        xt[(size_t)(b * HWn + hw0 + hwl) * Cn + lane] = tile[lane][hwl];
    }
}

// ---- Kernel 2: 18-channel 3x3 offset conv (NCHW direct) ----
__global__ __launch_bounds__(256) void k_offset_conv(const float* __restrict__ x,
                                                     const float* __restrict__ w_off,
                                                     const float* __restrict__ b_off,
                                                     float* __restrict__ off) {
    const int idx = blockIdx.x * 256 + threadIdx.x;
    const int xx = idx & (Wn - 1);
    const int yy = (idx >> 7) & (Hn - 1);
    const int ch = (idx >> 14) % 18;
    const int b  = idx / (18 * HWn);
    float acc = b_off[ch];
    const float* xb = x + (size_t)b * Cn * HWn;
    const float* wb = w_off + ch * CKn;
#pragma unroll
    for (int ky = 0; ky < 3; ++ky) {
        const int sy = yy + ky - 1;
        if (sy < 0 || sy >= Hn) continue;
#pragma unroll
        for (int kx = 0; kx < 3; ++kx) {
            const int sx = xx + kx - 1;
            if (sx < 0 || sx >= Wn) continue;
            const float* xp = xb + sy * Wn + sx;
            const float* wq = wb + ky * 3 + kx;
#pragma unroll 8
            for (int c = 0; c < Cn; ++c)
                acc = fmaf(xp[c * HWn], wq[c * 9], acc);
        }
    }
    off[idx] = acc;
}

// ---- Kernel 2b: w_def fp32 -> bf16 A-fragment swizzle ----
// A-frag convention (16x16x32): lane l holds A[row = 16*r + (l&15)]
//   [k = 32*s + 4*(l>>4) + (j&3) + 16*(j>>2)], j = 0..7, stored contiguously:
//   aswz[ ((r*18 + s)*64 + l)*8 + j ]
__global__ __launch_bounds__(256) void k_prep(const float* __restrict__ w_def,
                                              unsigned short* __restrict__ aswz) {
    const int idx = blockIdx.x * 256 + threadIdx.x;   // [0, 36864)
    const int j = idx & 7;
    const int l = (idx >> 3) & 63;
    const int s = (idx >> 9) % 18;
    const int r = idx / 9216;
    const int co = 16 * r + (l & 15);
    const int k  = 32 * s + 4 * (l >> 4) + (j & 3) + 16 * (j >> 2);
    aswz[idx] = f2bf(w_def[co * CKn + k]);
}

// ---- Kernel 3: bilinear gather (phase 1) + MFMA contraction (phase 2) ----
__global__ __launch_bounds__(256) void k_deform(const float* __restrict__ xt,
                                                const float* __restrict__ off,
                                                const unsigned short* __restrict__ aswz,
                                                float* __restrict__ out) {
    __shared__ unsigned short Bl[TILE * RS];   // 37120 B, px-major bf16 panel
    const int tid  = threadIdx.x;
    const int lane = tid & 63;
    const int wid  = tid >> 6;
    const int b    = blockIdx.x >> 9;            // 512 tiles per batch
    const int p0   = (blockIdx.x & 511) * TILE;  // 32 consecutive pixels (same row)

    // Phase 1: lane = input channel; each wave gathers 8 pixels x 9 taps
    const float* xtb = xt + (size_t)(b * HWn) * Cn + lane;
    for (int pg = 0; pg < 8; ++pg) {
        const int pix = (wid << 3) + pg;
        const int p   = p0 + pix;
        const int oy  = p >> 7;
        const int ox  = p & (Wn - 1);
        const float* offp = off + (size_t)(b * 18) * HWn + p;
        unsigned short* brow = &Bl[pix * RS + lane * 9];
#pragma unroll
        for (int k = 0; k < 9; ++k) {
            const float dyo = offp[(2 * k) * HWn];
            const float dxo = offp[(2 * k + 1) * HWn];
            const float py = dyo + (float)(oy + k / 3 - 1);
            const float px = dxo + (float)(ox + k % 3 - 1);
            const float fy = floorf(py);
            const float fx = floorf(px);
            const float ay = py - fy;
            const float ax = px - fx;
            const int iy0 = (int)fy;
            const int ix0 = (int)fx;
            const float w00 = (1.f - ay) * (1.f - ax);
            const float w01 = (1.f - ay) * ax;
            const float w10 = ay * (1.f - ax);
            const float w11 = ay * ax;
            float v = 0.f;
            const bool x0ok = (ix0 >= 0) & (ix0 < Wn);
            const bool x1ok = (ix0 + 1 >= 0) & (ix0 + 1 < Wn);
            if (iy0 >= 0 && iy0 < Hn) {
                const float* row = xtb + (size_t)(iy0 * Wn) * Cn;
                if (x0ok) v = fmaf(w00, row[ix0 * Cn], v);
                if (x1ok) v = fmaf(w01, row[(ix0 + 1) * Cn], v);
            }
            if (iy0 + 1 >= 0 && iy0 + 1 < Hn) {
                const float* row = xtb + (size_t)((iy0 + 1) * Wn) * Cn;
                if (x0ok) v = fmaf(w10, row[ix0 * Cn], v);
                if (x1ok) v = fmaf(w11, row[(ix0 + 1) * Cn], v);
            }
            brow[k] = f2bf(v);   // ck = lane*9 + k, matches w_def.reshape(Co, C*9)
        }
    }
    __syncthreads();

    // Phase 2: wave wid computes co rows [16*wid, 16*wid+16) x 32 pixels.
    // B frag: col = nb*16 + (lane&15), k-group by lane>>4 (same convention as A).
    v4f acc0 = {0.f, 0.f, 0.f, 0.f};
    v4f acc1 = {0.f, 0.f, 0.f, 0.f};
    const int g   = lane >> 4;
    const int c15 = lane & 15;
    const unsigned short* arow = aswz + (size_t)wid * 9216 + lane * 8;
#pragma unroll
    for (int s = 0; s < 18; ++s) {
        const v8s a = *reinterpret_cast<const v8s*>(arow + s * 512);
        const int kb = 32 * s + 4 * g;
        const unsigned short* b0p = &Bl[c15 * RS + kb];
        const v4s lo0 = *reinterpret_cast<const v4s*>(b0p);
        const v4s hi0 = *reinterpret_cast<const v4s*>(b0p + 16);
        const unsigned short* b1p = b0p + 16 * RS;
        const v4s lo1 = *reinterpret_cast<const v4s*>(b1p);
        const v4s hi1 = *reinterpret_cast<const v4s*>(b1p + 16);
        const v8s bb0 = {lo0[0], lo0[1], lo0[2], lo0[3], hi0[0], hi0[1], hi0[2], hi0[3]};
        const v8s bb1 = {lo1[0], lo1[1], lo1[2], lo1[3], hi1[0], hi1[1], hi1[2], hi1[3]};
        acc0 = __builtin_amdgcn_mfma_f32_16x16x32_bf16(a, bb0, acc0, 0, 0, 0);
        acc1 = __builtin_amdgcn_mfma_f32_16x16x32_bf16(a, bb1, acc1, 0, 0, 0);
    }
    // D layout (verified): row(co) = 4*(lane>>4) + r, col(px) = lane&15
    const int co = (wid << 4) + (g << 2);
    float* op = out + ((size_t)(b * COn + co)) * HWn + p0 + c15;
#pragma unroll
    for (int r = 0; r < 4; ++r) {
        op[(size_t)r * HWn]      = acc0[r];
        op[(size_t)r * HWn + 16] = acc1[r];
    }
}

extern "C" void kernel_launch(void* const* d_in, const int* in_sizes, int n_in,
                              void* d_out, int out_size, void* d_ws, size_t ws_size,
                              hipStream_t stream) {
    const float* x     = (const float*)d_in[0];
    const float* w_off = (const float*)d_in[1];
    const float* b_off = (const float*)d_in[2];
    const float* w_def = (const float*)d_in[3];
    float* outp = (float*)d_out;
    float* wsf  = (float*)d_ws;
    float* xt   = wsf + XT_OFF;
    unsigned short* aswz = (unsigned short*)(wsf + ASWZ_OFF);
    float* off  = wsf + OFF_OFF;

    k_transpose<<<Bn * 256, 256, 0, stream>>>(x, xt);
    k_offset_conv<<<(Bn * 18 * HWn) / 256, 256, 0, stream>>>(x, w_off, b_off, off);
    k_prep<<<144, 256, 0, stream>>>(w_def, aswz);
    k_deform<<<Bn * (HWn / TILE), 256, 0, stream>>>(xt, off, aswz, outp);
}

// Round 3
// 179.343 us; speedup vs baseline: 2.8334x; 1.6875x over previous
//
#include <hip/hip_runtime.h>
#include <math.h>

// Deformable conv fwd: B=4, C=CO=64, H=W=128, K=3, pad=1, stride=1.
// ws layout (float units):
//   [0, 4194304)              xt: x transposed to NHWC (16 MiB)
//   [4194304, 4212736)        aswz: w_def bf16 A-frags (72 KiB)
//   [4212736, 4221952)        aoff: w_off bf16 A-frags, rows padded to 32 (36 KiB)

typedef short  v4s __attribute__((ext_vector_type(4)));
typedef short  v8s __attribute__((ext_vector_type(8)));
typedef float  v4f __attribute__((ext_vector_type(4)));

namespace {
constexpr int Bn = 4, Cn = 64, Hn = 128, Wn = 128, COn = 64;
constexpr int HWn = Hn * Wn;            // 16384
constexpr int CKn = Cn * 9;             // 576
constexpr int TILE = 32;                // pixels per block in main kernel
constexpr int RS = 580;                 // LDS row stride in bf16 (1160 B = 290 dw ≡ 2 mod 32)
constexpr size_t XT_OFF   = 0;
constexpr size_t ASWZ_OFF = (size_t)Bn * HWn * Cn;   // float index 4194304
constexpr size_t AOFF_OFF = ASWZ_OFF + 18432;        // aswz = 36864 bf16 = 18432 floats
}

__device__ __forceinline__ unsigned short f2bf(float f) {
    union { float f; unsigned int u; } v; v.f = f;
    unsigned int u = v.u;
    u += 0x7fffu + ((u >> 16) & 1u);    // round-to-nearest-even
    return (unsigned short)(u >> 16);
}

// ---- Kernel 1: NCHW -> NHWC transpose of x ----
__global__ __launch_bounds__(256) void k_transpose(const float* __restrict__ x,
                                                   float* __restrict__ xt) {
    __shared__ float tile[64][65];
    const int tid  = threadIdx.x;
    const int lane = tid & 63;
    const int grp  = tid >> 6;
    const int b    = blockIdx.x >> 8;
    const int hw0  = (blockIdx.x & 255) << 6;
#pragma unroll
    for (int r = 0; r < 16; ++r) {
        const int c = (r << 2) + grp;
        tile[c][lane] = x[(b * Cn + c) * HWn + hw0 + lane];
    }
    __syncthreads();
#pragma unroll
    for (int r = 0; r < 16; ++r) {
        const int hwl = (r << 2) + grp;
        xt[(size_t)(b * HWn + hw0 + hwl) * Cn + lane] = tile[lane][hwl];
    }
}

// ---- Kernel 2: weight swizzle to MFMA A-frag layout (w_def + w_off) ----
// A-frag (16x16x32): lane l holds A[row = 16*r + (l&15)]
//   [k = 32*s + 4*(l>>4) + (j&3) + 16*(j>>2)], j = 0..7:
//   frag[((r*NS + s)*64 + l)*8 + j]
__global__ __launch_bounds__(256) void k_prep(const float* __restrict__ w_def,
                                              const float* __restrict__ w_off,
                                              unsigned short* __restrict__ aswz,
                                              unsigned short* __restrict__ aoff) {
    const int idx = blockIdx.x * 256 + threadIdx.x;   // [0, 36864+18432)
    if (idx < 36864) {
        const int j = idx & 7;
        const int l = (idx >> 3) & 63;
        const int s = (idx >> 9) % 18;
        const int r = idx / 9216;
        const int co = 16 * r + (l & 15);
        const int k  = 32 * s + 4 * (l >> 4) + (j & 3) + 16 * (j >> 2);
        aswz[idx] = f2bf(w_def[co * CKn + k]);
    } else {
        const int i2 = idx - 36864;                   // [0, 18432)
        const int j = i2 & 7;
        const int l = (i2 >> 3) & 63;
        const int s = (i2 >> 9) % 18;
        const int r = i2 / 9216;                      // row-tile 0/1
        const int co = 16 * r + (l & 15);             // [0,32), valid < 18
        const int k  = 32 * s + 4 * (l >> 4) + (j & 3) + 16 * (j >> 2);
        aoff[i2] = (co < 18) ? f2bf(w_off[co * CKn + k]) : (unsigned short)0;
    }
}

// ---- Kernel 3: fused offset-conv (MFMA) + bilinear gather + MFMA contraction ----
__global__ __launch_bounds__(256) void k_deform(const float* __restrict__ xt,
                                                const unsigned short* __restrict__ aoff,
                                                const float* __restrict__ b_off,
                                                const unsigned short* __restrict__ aswz,
                                                float* __restrict__ out) {
    __shared__ unsigned short Bl[TILE * RS];   // 37120 B; patch panel, then sampled panel
    __shared__ float part[4][18][32];          // 9216 B, per-wave offset partials
    __shared__ float offl[18][32];             // 2304 B, final offsets
    const int tid  = threadIdx.x;
    const int lane = tid & 63;
    const int wid  = tid >> 6;
    const int g    = lane >> 4;
    const int c15  = lane & 15;
    const int b    = blockIdx.x >> 9;            // 512 tiles per batch
    const int p0   = (blockIdx.x & 511) * TILE;  // 32 consecutive pixels (same row)
    const float* xtb = xt + (size_t)(b * HWn) * Cn + lane;

    // ---- Phase 0a: regular-grid im2col panel P[pix][ck] (bf16) ----
    for (int pg = 0; pg < 8; ++pg) {
        const int pix = (wid << 3) + pg;
        const int p   = p0 + pix;
        const int oy  = p >> 7;
        const int ox  = p & (Wn - 1);
        unsigned short* brow = &Bl[pix * RS + lane * 9];
#pragma unroll
        for (int k = 0; k < 9; ++k) {
            const int sy = oy + k / 3 - 1;
            const int sx = ox + k % 3 - 1;
            float v = 0.f;
            if (sy >= 0 && sy < Hn && sx >= 0 && sx < Wn)
                v = xtb[(size_t)(sy * Wn + sx) * Cn];
            brow[k] = f2bf(v);
        }
    }
    __syncthreads();

    // ---- Phase 0b: off[18][32] = w_off . P via MFMA, k-split across waves ----
    {
        v4f pa00 = {0.f,0.f,0.f,0.f}, pa01 = {0.f,0.f,0.f,0.f};
        v4f pa10 = {0.f,0.f,0.f,0.f}, pa11 = {0.f,0.f,0.f,0.f};
        for (int s = wid; s < 18; s += 4) {
            const int kb = 32 * s + 4 * g;
            const unsigned short* b0p = &Bl[c15 * RS + kb];
            const v4s lo0 = *reinterpret_cast<const v4s*>(b0p);
            const v4s hi0 = *reinterpret_cast<const v4s*>(b0p + 16);
            const v4s lo1 = *reinterpret_cast<const v4s*>(b0p + 16 * RS);
            const v4s hi1 = *reinterpret_cast<const v4s*>(b0p + 16 * RS + 16);
            const v8s bb0 = {lo0[0],lo0[1],lo0[2],lo0[3],hi0[0],hi0[1],hi0[2],hi0[3]};
            const v8s bb1 = {lo1[0],lo1[1],lo1[2],lo1[3],hi1[0],hi1[1],hi1[2],hi1[3]};
            const v8s a0 = *reinterpret_cast<const v8s*>(aoff + (size_t)(0 * 18 + s) * 512 + lane * 8);
            const v8s a1 = *reinterpret_cast<const v8s*>(aoff + (size_t)(1 * 18 + s) * 512 + lane * 8);
            pa00 = __builtin_amdgcn_mfma_f32_16x16x32_bf16(a0, bb0, pa00, 0, 0, 0);
            pa01 = __builtin_amdgcn_mfma_f32_16x16x32_bf16(a0, bb1, pa01, 0, 0, 0);
            pa10 = __builtin_amdgcn_mfma_f32_16x16x32_bf16(a1, bb0, pa10, 0, 0, 0);
            pa11 = __builtin_amdgcn_mfma_f32_16x16x32_bf16(a1, bb1, pa11, 0, 0, 0);
        }
#pragma unroll
        for (int r = 0; r < 4; ++r) {
            const int co0 = (g << 2) + r;        // row-tile 0: rows 0..15, all valid
            part[wid][co0][c15]      = pa00[r];
            part[wid][co0][16 + c15] = pa01[r];
            const int co1 = 16 + (g << 2) + r;   // row-tile 1: only 16,17 valid
            if (co1 < 18) {
                part[wid][co1][c15]      = pa10[r];
                part[wid][co1][16 + c15] = pa11[r];
            }
        }
    }
    __syncthreads();
    for (int idx = tid; idx < 576; idx += 256) {
        const int ch = idx >> 5, px = idx & 31;
        offl[ch][px] = part[0][ch][px] + part[1][ch][px] + part[2][ch][px]
                     + part[3][ch][px] + b_off[ch];
    }
    __syncthreads();

    // ---- Phase 1: bilinear gather -> sampled panel (overwrites Bl) ----
    for (int pg = 0; pg < 8; ++pg) {
        const int pix = (wid << 3) + pg;
        const int p   = p0 + pix;
        const int oy  = p >> 7;
        const int ox  = p & (Wn - 1);
        unsigned short* brow = &Bl[pix * RS + lane * 9];
#pragma unroll
        for (int k = 0; k < 9; ++k) {
            const float dyo = offl[2 * k][pix];       // LDS broadcast
            const float dxo = offl[2 * k + 1][pix];
            const float py = dyo + (float)(oy + k / 3 - 1);
            const float px = dxo + (float)(ox + k % 3 - 1);
            const float fy = floorf(py);
            const float fx = floorf(px);
            const float ay = py - fy;
            const float ax = px - fx;
            const int iy0 = (int)fy;
            const int ix0 = (int)fx;
            const float w00 = (1.f - ay) * (1.f - ax);
            const float w01 = (1.f - ay) * ax;
            const float w10 = ay * (1.f - ax);
            const float w11 = ay * ax;
            float v = 0.f;
            const bool x0ok = (ix0 >= 0) & (ix0 < Wn);
            const bool x1ok = (ix0 + 1 >= 0) & (ix0 + 1 < Wn);
            if (iy0 >= 0 && iy0 < Hn) {
                const float* row = xtb + (size_t)(iy0 * Wn) * Cn;
                if (x0ok) v = fmaf(w00, row[ix0 * Cn], v);
                if (x1ok) v = fmaf(w01, row[(ix0 + 1) * Cn], v);
            }
            if (iy0 + 1 >= 0 && iy0 + 1 < Hn) {
                const float* row = xtb + (size_t)((iy0 + 1) * Wn) * Cn;
                if (x0ok) v = fmaf(w10, row[ix0 * Cn], v);
                if (x1ok) v = fmaf(w11, row[(ix0 + 1) * Cn], v);
            }
            brow[k] = f2bf(v);
        }
    }
    __syncthreads();

    // ---- Phase 2: out = w_def . sampled via MFMA ----
    v4f acc0 = {0.f,0.f,0.f,0.f};
    v4f acc1 = {0.f,0.f,0.f,0.f};
    const unsigned short* arow = aswz + (size_t)wid * 9216 + lane * 8;
#pragma unroll
    for (int s = 0; s < 18; ++s) {
        const v8s a = *reinterpret_cast<const v8s*>(arow + s * 512);
        const int kb = 32 * s + 4 * g;
        const unsigned short* b0p = &Bl[c15 * RS + kb];
        const v4s lo0 = *reinterpret_cast<const v4s*>(b0p);
        const v4s hi0 = *reinterpret_cast<const v4s*>(b0p + 16);
        const v4s lo1 = *reinterpret_cast<const v4s*>(b0p + 16 * RS);
        const v4s hi1 = *reinterpret_cast<const v4s*>(b0p + 16 * RS + 16);
        const v8s bb0 = {lo0[0],lo0[1],lo0[2],lo0[3],hi0[0],hi0[1],hi0[2],hi0[3]};
        const v8s bb1 = {lo1[0],lo1[1],lo1[2],lo1[3],hi1[0],hi1[1],hi1[2],hi1[3]};
        acc0 = __builtin_amdgcn_mfma_f32_16x16x32_bf16(a, bb0, acc0, 0, 0, 0);
        acc1 = __builtin_amdgcn_mfma_f32_16x16x32_bf16(a, bb1, acc1, 0, 0, 0);
    }
    const int co = (wid << 4) + (g << 2);
    float* op = out + ((size_t)(b * COn + co)) * HWn + p0 + c15;
#pragma unroll
    for (int r = 0; r < 4; ++r) {
        op[(size_t)r * HWn]      = acc0[r];
        op[(size_t)r * HWn + 16] = acc1[r];
    }
}

extern "C" void kernel_launch(void* const* d_in, const int* in_sizes, int n_in,
                              void* d_out, int out_size, void* d_ws, size_t ws_size,
                              hipStream_t stream) {
    const float* x     = (const float*)d_in[0];
    const float* w_off = (const float*)d_in[1];
    const float* b_off = (const float*)d_in[2];
    const float* w_def = (const float*)d_in[3];
    float* outp = (float*)d_out;
    float* wsf  = (float*)d_ws;
    float* xt   = wsf + XT_OFF;
    unsigned short* aswz = (unsigned short*)(wsf + ASWZ_OFF);
    unsigned short* aoff = (unsigned short*)(wsf + AOFF_OFF);

    k_transpose<<<Bn * 256, 256, 0, stream>>>(x, xt);
    k_prep<<<216, 256, 0, stream>>>(w_def, w_off, aswz, aoff);
    k_deform<<<Bn * (HWn / TILE), 256, 0, stream>>>(xt, aoff, b_off, aswz, outp);
}

// Round 4
// 103.362 us; speedup vs baseline: 4.9162x; 1.7351x over previous
//
#include <hip/hip_runtime.h>
#include <math.h>

// Deformable conv fwd: B=4, C=CO=64, H=W=128, K=3, pad=1, stride=1.
// ws layout (float units):
//   [0, 4194304)              xt: x transposed to NHWC (16 MiB)
//   [4194304, 4212736)        aswz: w_def bf16 A-frags (72 KiB)
//   [4212736, 4221952)        aoff: w_off bf16 A-frags, rows padded to 32 (36 KiB)
// Panel k-order is TAP-MAJOR: ck' = tap*64 + c  (A-swizzle matches).

typedef short  v4s __attribute__((ext_vector_type(4)));
typedef short  v8s __attribute__((ext_vector_type(8)));
typedef float  v4f __attribute__((ext_vector_type(4)));

namespace {
constexpr int Bn = 4, Cn = 64, Hn = 128, Wn = 128, COn = 64;
constexpr int HWn = 16384;
constexpr int CKn = 576;
constexpr int TILE = 32;
constexpr int RS = 580;                 // shorts per panel row = 290 dwords (≡2 mod 32)
constexpr size_t XT_OFF   = 0;
constexpr size_t ASWZ_OFF = (size_t)Bn * HWn * Cn;   // float index 4194304
constexpr size_t AOFF_OFF = ASWZ_OFF + 18432;
}

__device__ __forceinline__ unsigned short f2bf(float f) {
    union { float f; unsigned int u; } v; v.f = f;
    unsigned int u = v.u;
    u += 0x7fffu + ((u >> 16) & 1u);    // RNE
    return (unsigned short)(u >> 16);
}
__device__ __forceinline__ unsigned int pack2bf(float a, float b) {
    return (unsigned int)f2bf(a) | ((unsigned int)f2bf(b) << 16);
}

// ---- Kernel 1: NCHW -> NHWC transpose of x ----
__global__ __launch_bounds__(256) void k_transpose(const float* __restrict__ x,
                                                   float* __restrict__ xt) {
    __shared__ float tile[64][65];
    const int tid  = threadIdx.x;
    const int lane = tid & 63;
    const int grp  = tid >> 6;
    const int b    = blockIdx.x >> 8;
    const int hw0  = (blockIdx.x & 255) << 6;
#pragma unroll
    for (int r = 0; r < 16; ++r) {
        const int c = (r << 2) + grp;
        tile[c][lane] = x[(b * Cn + c) * HWn + hw0 + lane];
    }
    __syncthreads();
#pragma unroll
    for (int r = 0; r < 16; ++r) {
        const int hwl = (r << 2) + grp;
        xt[(size_t)(b * HWn + hw0 + hwl) * Cn + lane] = tile[lane][hwl];
    }
}

// ---- Kernel 2: weight swizzle to MFMA A-frag layout, tap-major k ----
// lane l holds A[row=16r+(l&15)][k = 32s+4(l>>4)+(j&3)+16(j>>2)], ck' = tap*64+c
__global__ __launch_bounds__(256) void k_prep(const float* __restrict__ w_def,
                                              const float* __restrict__ w_off,
                                              unsigned short* __restrict__ aswz,
                                              unsigned short* __restrict__ aoff) {
    const int idx = blockIdx.x * 256 + threadIdx.x;   // [0, 36864+18432)
    if (idx < 36864) {
        const int j = idx & 7;
        const int l = (idx >> 3) & 63;
        const int s = (idx >> 9) % 18;
        const int r = idx / 9216;
        const int co = 16 * r + (l & 15);
        const int kk = 32 * s + 4 * (l >> 4) + (j & 3) + 16 * (j >> 2);
        const int tap = kk >> 6, c = kk & 63;
        aswz[idx] = f2bf(w_def[co * CKn + c * 9 + tap]);
    } else {
        const int i2 = idx - 36864;
        const int j = i2 & 7;
        const int l = (i2 >> 3) & 63;
        const int s = (i2 >> 9) % 18;
        const int r = i2 / 9216;
        const int co = 16 * r + (l & 15);
        const int kk = 32 * s + 4 * (l >> 4) + (j & 3) + 16 * (j >> 2);
        const int tap = kk >> 6, c = kk & 63;
        aoff[i2] = (co < 18) ? f2bf(w_off[co * CKn + c * 9 + tap]) : (unsigned short)0;
    }
}

// ---- Kernel 3: fused offset MFMA + bilinear gather + output MFMA ----
__global__ __launch_bounds__(256, 4) void k_deform(const float* __restrict__ xt,
                                                   const unsigned short* __restrict__ aoff,
                                                   const float* __restrict__ b_off,
                                                   const unsigned short* __restrict__ aswz,
                                                   float* __restrict__ out) {
    __shared__ unsigned short Bl[TILE * RS];   // 37120 B panel (tap-major)
    __shared__ float offl[18][32];             // 2304 B offsets
    unsigned int* Bld = (unsigned int*)Bl;
    const int tid  = threadIdx.x;
    const int lane = tid & 63;
    const int wid  = tid >> 6;
    const int g    = lane >> 4;
    const int c15  = lane & 15;
    const int h    = lane >> 5;     // pixel-half
    const int m    = lane & 31;     // channel-pair index
    const int b    = blockIdx.x >> 9;
    const int p0   = (blockIdx.x & 511) * TILE;
    const float* xc = xt + (size_t)(b * HWn) * Cn + 2 * m;  // float2 channel base

    // ---- Phase 0a: regular-grid im2col panel (tap-major, float2) ----
#pragma unroll
    for (int ip = 0; ip < 4; ++ip) {
        const int pix = (wid << 3) + (ip << 1) + h;
        const int p   = p0 + pix;
        const int oy  = p >> 7;
        const int ox  = p & (Wn - 1);
        const int dbase = pix * 290 + m;
#pragma unroll
        for (int k = 0; k < 9; ++k) {
            const int sy = oy + k / 3 - 1;
            const int sx = ox + k % 3 - 1;
            float vx = 0.f, vy = 0.f;
            if ((unsigned)sy < (unsigned)Hn && (unsigned)sx < (unsigned)Wn) {
                const float2 t = *reinterpret_cast<const float2*>(xc + (size_t)(sy * Wn + sx) * Cn);
                vx = t.x; vy = t.y;
            }
            Bld[dbase + k * 32] = pack2bf(vx, vy);
        }
    }
    __syncthreads();

    // ---- Phase 0b: off = w_off . P via MFMA (all waves redundant; wave0 writes) ----
    {
        v4f pa00 = {0.f,0.f,0.f,0.f}, pa01 = {0.f,0.f,0.f,0.f};
        v4f pa10 = {0.f,0.f,0.f,0.f}, pa11 = {0.f,0.f,0.f,0.f};
#pragma unroll
        for (int s = 0; s < 18; ++s) {
            const int kb = 32 * s + 4 * g;
            const unsigned short* b0p = &Bl[c15 * RS + kb];
            const v4s lo0 = *reinterpret_cast<const v4s*>(b0p);
            const v4s hi0 = *reinterpret_cast<const v4s*>(b0p + 16);
            const v4s lo1 = *reinterpret_cast<const v4s*>(b0p + 16 * RS);
            const v4s hi1 = *reinterpret_cast<const v4s*>(b0p + 16 * RS + 16);
            const v8s bb0 = {lo0[0],lo0[1],lo0[2],lo0[3],hi0[0],hi0[1],hi0[2],hi0[3]};
            const v8s bb1 = {lo1[0],lo1[1],lo1[2],lo1[3],hi1[0],hi1[1],hi1[2],hi1[3]};
            const v8s a0 = *reinterpret_cast<const v8s*>(aoff + (size_t)(0 * 18 + s) * 512 + lane * 8);
            const v8s a1 = *reinterpret_cast<const v8s*>(aoff + (size_t)(1 * 18 + s) * 512 + lane * 8);
            pa00 = __builtin_amdgcn_mfma_f32_16x16x32_bf16(a0, bb0, pa00, 0, 0, 0);
            pa01 = __builtin_amdgcn_mfma_f32_16x16x32_bf16(a0, bb1, pa01, 0, 0, 0);
            pa10 = __builtin_amdgcn_mfma_f32_16x16x32_bf16(a1, bb0, pa10, 0, 0, 0);
            pa11 = __builtin_amdgcn_mfma_f32_16x16x32_bf16(a1, bb1, pa11, 0, 0, 0);
        }
        if (wid == 0) {
#pragma unroll
            for (int r = 0; r < 4; ++r) {
                const int co0 = (g << 2) + r;
                const float bo0 = b_off[co0];
                offl[co0][c15]      = pa00[r] + bo0;
                offl[co0][c15 + 16] = pa01[r] + bo0;
                const int co1 = 16 + (g << 2) + r;
                if (co1 < 18) {
                    const float bo1 = b_off[co1];
                    offl[co1][c15]      = pa10[r] + bo1;
                    offl[co1][c15 + 16] = pa11[r] + bo1;
                }
            }
        }
    }
    __syncthreads();

    // ---- Phase 1: bilinear gather -> panel (overwrites Bl; tap-major, float2) ----
#pragma unroll
    for (int ip = 0; ip < 4; ++ip) {
        const int pix = (wid << 3) + (ip << 1) + h;
        const int p   = p0 + pix;
        const int oy  = p >> 7;
        const int ox  = p & (Wn - 1);
        const int dbase = pix * 290 + m;
#pragma unroll
        for (int k = 0; k < 9; ++k) {
            const float py = offl[2 * k][pix]     + (float)(oy + k / 3 - 1);
            const float px = offl[2 * k + 1][pix] + (float)(ox + k % 3 - 1);
            const float fy = floorf(py);
            const float fx = floorf(px);
            const float ay = py - fy;
            const float ax = px - fx;
            const int iy0 = (int)fy;
            const int ix0 = (int)fx;
            const float w00 = (1.f - ay) * (1.f - ax);
            const float w01 = (1.f - ay) * ax;
            const float w10 = ay * (1.f - ax);
            const float w11 = ay * ax;
            float vx = 0.f, vy = 0.f;
            const bool x0ok = (unsigned)ix0 < (unsigned)Wn;
            const bool x1ok = (unsigned)(ix0 + 1) < (unsigned)Wn;
            const float* r0 = xc + (ptrdiff_t)iy0 * (Wn * Cn);
            if ((unsigned)iy0 < (unsigned)Hn) {
                if (x0ok) { const float2 t = *reinterpret_cast<const float2*>(r0 + ix0 * Cn);
                            vx = fmaf(w00, t.x, vx); vy = fmaf(w00, t.y, vy); }
                if (x1ok) { const float2 t = *reinterpret_cast<const float2*>(r0 + ix0 * Cn + Cn);
                            vx = fmaf(w01, t.x, vx); vy = fmaf(w01, t.y, vy); }
            }
            if ((unsigned)(iy0 + 1) < (unsigned)Hn) {
                const float* r1 = r0 + Wn * Cn;
                if (x0ok) { const float2 t = *reinterpret_cast<const float2*>(r1 + ix0 * Cn);
                            vx = fmaf(w10, t.x, vx); vy = fmaf(w10, t.y, vy); }
                if (x1ok) { const float2 t = *reinterpret_cast<const float2*>(r1 + ix0 * Cn + Cn);
                            vx = fmaf(w11, t.x, vx); vy = fmaf(w11, t.y, vy); }
            }
            Bld[dbase + k * 32] = pack2bf(vx, vy);
        }
    }
    __syncthreads();

    // ---- Phase 2: out = w_def . sampled via MFMA ----
    v4f acc0 = {0.f,0.f,0.f,0.f};
    v4f acc1 = {0.f,0.f,0.f,0.f};
    const unsigned short* arow = aswz + (size_t)wid * 9216 + lane * 8;
#pragma unroll
    for (int s = 0; s < 18; ++s) {
        const v8s a = *reinterpret_cast<const v8s*>(arow + s * 512);
        const int kb = 32 * s + 4 * g;
        const unsigned short* b0p = &Bl[c15 * RS + kb];
        const v4s lo0 = *reinterpret_cast<const v4s*>(b0p);
        const v4s hi0 = *reinterpret_cast<const v4s*>(b0p + 16);
        const v4s lo1 = *reinterpret_cast<const v4s*>(b0p + 16 * RS);
        const v4s hi1 = *reinterpret_cast<const v4s*>(b0p + 16 * RS + 16);
        const v8s bb0 = {lo0[0],lo0[1],lo0[2],lo0[3],hi0[0],hi0[1],hi0[2],hi0[3]};
        const v8s bb1 = {lo1[0],lo1[1],lo1[2],lo1[3],hi1[0],hi1[1],hi1[2],hi1[3]};
        acc0 = __builtin_amdgcn_mfma_f32_16x16x32_bf16(a, bb0, acc0, 0, 0, 0);
        acc1 = __builtin_amdgcn_mfma_f32_16x16x32_bf16(a, bb1, acc1, 0, 0, 0);
    }
    const int co = (wid << 4) + (g << 2);
    float* op = out + ((size_t)(b * COn + co)) * HWn + p0 + c15;
#pragma unroll
    for (int r = 0; r < 4; ++r) {
        op[(size_t)r * HWn]      = acc0[r];
        op[(size_t)r * HWn + 16] = acc1[r];
    }
}

extern "C" void kernel_launch(void* const* d_in, const int* in_sizes, int n_in,
                              void* d_out, int out_size, void* d_ws, size_t ws_size,
                              hipStream_t stream) {
    const float* x     = (const float*)d_in[0];
    const float* w_off = (const float*)d_in[1];
    const float* b_off = (const float*)d_in[2];
    const float* w_def = (const float*)d_in[3];
    float* outp = (float*)d_out;
    float* wsf  = (float*)d_ws;
    float* xt   = wsf + XT_OFF;
    unsigned short* aswz = (unsigned short*)(wsf + ASWZ_OFF);
    unsigned short* aoff = (unsigned short*)(wsf + AOFF_OFF);

    k_transpose<<<Bn * 256, 256, 0, stream>>>(x, xt);
    k_prep<<<216, 256, 0, stream>>>(w_def, w_off, aswz, aoff);
    k_deform<<<Bn * (HWn / TILE), 256, 0, stream>>>(xt, aoff, b_off, aswz, outp);
}

// Round 5
// 90.045 us; speedup vs baseline: 5.6432x; 1.1479x over previous
//
#include <hip/hip_runtime.h>
#include <math.h>

// Deformable conv fwd: B=4, C=CO=64, H=W=128, K=3, pad=1, stride=1.
// ws layout (float units):
//   [0, 4194304)              xt: x transposed to NHWC (16 MiB)
//   [4194304, 4212736)        aswz: w_def bf16 A-frags (72 KiB)
//   [4212736, 4221952)        aoff: w_off bf16 A-frags, rows padded to 32 (36 KiB)
// Panel k-order is TAP-MAJOR: ck' = tap*64 + c  (A-swizzle matches).

typedef short  v4s __attribute__((ext_vector_type(4)));
typedef short  v8s __attribute__((ext_vector_type(8)));
typedef float  v4f __attribute__((ext_vector_type(4)));

namespace {
constexpr int Bn = 4, Cn = 64, Hn = 128, Wn = 128, COn = 64;
constexpr int HWn = 16384;
constexpr int CKn = 576;
constexpr int TILE = 16;                // pixels per block
constexpr int RS = 580;                 // shorts per panel row = 290 dwords (≡2 mod 32)
constexpr size_t XT_OFF   = 0;
constexpr size_t ASWZ_OFF = (size_t)Bn * HWn * Cn;   // float index 4194304
constexpr size_t AOFF_OFF = ASWZ_OFF + 18432;
}

__device__ __forceinline__ unsigned short f2bf(float f) {
    union { float f; unsigned int u; } v; v.f = f;
    unsigned int u = v.u;
    u += 0x7fffu + ((u >> 16) & 1u);    // RNE
    return (unsigned short)(u >> 16);
}
__device__ __forceinline__ unsigned int pack2bf(float a, float b) {
    return (unsigned int)f2bf(a) | ((unsigned int)f2bf(b) << 16);
}

// ---- Kernel 1: NCHW -> NHWC transpose of x ----
__global__ __launch_bounds__(256) void k_transpose(const float* __restrict__ x,
                                                   float* __restrict__ xt) {
    __shared__ float tile[64][65];
    const int tid  = threadIdx.x;
    const int lane = tid & 63;
    const int grp  = tid >> 6;
    const int b    = blockIdx.x >> 8;
    const int hw0  = (blockIdx.x & 255) << 6;
#pragma unroll
    for (int r = 0; r < 16; ++r) {
        const int c = (r << 2) + grp;
        tile[c][lane] = x[(b * Cn + c) * HWn + hw0 + lane];
    }
    __syncthreads();
#pragma unroll
    for (int r = 0; r < 16; ++r) {
        const int hwl = (r << 2) + grp;
        xt[(size_t)(b * HWn + hw0 + hwl) * Cn + lane] = tile[lane][hwl];
    }
}

// ---- Kernel 2: weight swizzle to MFMA A-frag layout, tap-major k ----
// lane l holds A[row=16r+(l&15)][k = 32s+4(l>>4)+(j&3)+16(j>>2)], ck' = tap*64+c
__global__ __launch_bounds__(256) void k_prep(const float* __restrict__ w_def,
                                              const float* __restrict__ w_off,
                                              unsigned short* __restrict__ aswz,
                                              unsigned short* __restrict__ aoff) {
    const int idx = blockIdx.x * 256 + threadIdx.x;   // [0, 36864+18432)
    if (idx < 36864) {
        const int j = idx & 7;
        const int l = (idx >> 3) & 63;
        const int s = (idx >> 9) % 18;
        const int r = idx / 9216;
        const int co = 16 * r + (l & 15);
        const int kk = 32 * s + 4 * (l >> 4) + (j & 3) + 16 * (j >> 2);
        const int tap = kk >> 6, c = kk & 63;
        aswz[idx] = f2bf(w_def[co * CKn + c * 9 + tap]);
    } else {
        const int i2 = idx - 36864;
        const int j = i2 & 7;
        const int l = (i2 >> 3) & 63;
        const int s = (i2 >> 9) % 18;
        const int r = i2 / 9216;
        const int co = 16 * r + (l & 15);
        const int kk = 32 * s + 4 * (l >> 4) + (j & 3) + 16 * (j >> 2);
        const int tap = kk >> 6, c = kk & 63;
        aoff[i2] = (co < 18) ? f2bf(w_off[co * CKn + c * 9 + tap]) : (unsigned short)0;
    }
}

// ---- Kernel 3: fused offset MFMA + bilinear gather + output MFMA ----
__global__ __launch_bounds__(256, 8) void k_deform(const float* __restrict__ xt,
                                                   const unsigned short* __restrict__ aoff,
                                                   const float* __restrict__ b_off,
                                                   const unsigned short* __restrict__ aswz,
                                                   float* __restrict__ out) {
    __shared__ unsigned short Bl[TILE * RS];   // 18560 B panel (tap-major)
    __shared__ float offl[18][16];             // 1152 B offsets
    unsigned int* Bld = (unsigned int*)Bl;
    const int tid  = threadIdx.x;
    const int lane = tid & 63;
    const int wid  = tid >> 6;
    const int g    = lane >> 4;
    const int c15  = lane & 15;
    const int h    = lane >> 5;     // pixel-half
    const int m    = lane & 31;     // channel-pair index
    const int b    = blockIdx.x >> 10;           // 1024 tiles per batch
    const int p0   = (blockIdx.x & 1023) * TILE; // 16 consecutive pixels (same row)
    const float* xc = xt + (size_t)(b * HWn) * Cn + 2 * m;  // float2 channel base

    // ---- Phase 0a: regular-grid im2col panel (tap-major, float2) ----
#pragma unroll
    for (int ip = 0; ip < 2; ++ip) {
        const int pix = (wid << 2) + (ip << 1) + h;
        const int p   = p0 + pix;
        const int oy  = p >> 7;
        const int ox  = p & (Wn - 1);
        const int dbase = pix * 290 + m;
#pragma unroll
        for (int k = 0; k < 9; ++k) {
            const int sy = oy + k / 3 - 1;
            const int sx = ox + k % 3 - 1;
            float vx = 0.f, vy = 0.f;
            if ((unsigned)sy < (unsigned)Hn && (unsigned)sx < (unsigned)Wn) {
                const float2 t = *reinterpret_cast<const float2*>(xc + (size_t)(sy * Wn + sx) * Cn);
                vx = t.x; vy = t.y;
            }
            Bld[dbase + k * 32] = pack2bf(vx, vy);
        }
    }
    __syncthreads();

    // ---- Phase 0b: off = w_off . P via MFMA (all waves redundant; wave0 writes) ----
    {
        v4f pa00 = {0.f,0.f,0.f,0.f};
        v4f pa10 = {0.f,0.f,0.f,0.f};
#pragma unroll
        for (int s = 0; s < 18; ++s) {
            const int kb = 32 * s + 4 * g;
            const unsigned short* b0p = &Bl[c15 * RS + kb];
            const v4s lo0 = *reinterpret_cast<const v4s*>(b0p);
            const v4s hi0 = *reinterpret_cast<const v4s*>(b0p + 16);
            const v8s bb0 = {lo0[0],lo0[1],lo0[2],lo0[3],hi0[0],hi0[1],hi0[2],hi0[3]};
            const v8s a0 = *reinterpret_cast<const v8s*>(aoff + (size_t)(0 * 18 + s) * 512 + lane * 8);
            const v8s a1 = *reinterpret_cast<const v8s*>(aoff + (size_t)(1 * 18 + s) * 512 + lane * 8);
            pa00 = __builtin_amdgcn_mfma_f32_16x16x32_bf16(a0, bb0, pa00, 0, 0, 0);
            pa10 = __builtin_amdgcn_mfma_f32_16x16x32_bf16(a1, bb0, pa10, 0, 0, 0);
        }
        if (wid == 0) {
#pragma unroll
            for (int r = 0; r < 4; ++r) {
                const int co0 = (g << 2) + r;
                offl[co0][c15] = pa00[r] + b_off[co0];
                const int co1 = 16 + (g << 2) + r;
                if (co1 < 18)
                    offl[co1][c15] = pa10[r] + b_off[co1];
            }
        }
    }
    __syncthreads();

    // ---- Phase 1: bilinear gather -> panel (overwrites Bl; tap-major, float2) ----
#pragma unroll
    for (int ip = 0; ip < 2; ++ip) {
        const int pix = (wid << 2) + (ip << 1) + h;
        const int p   = p0 + pix;
        const int oy  = p >> 7;
        const int ox  = p & (Wn - 1);
        const int dbase = pix * 290 + m;
#pragma unroll
        for (int k = 0; k < 9; ++k) {
            const float py = offl[2 * k][pix]     + (float)(oy + k / 3 - 1);
            const float px = offl[2 * k + 1][pix] + (float)(ox + k % 3 - 1);
            const float fy = floorf(py);
            const float fx = floorf(px);
            const float ay = py - fy;
            const float ax = px - fx;
            const int iy0 = (int)fy;
            const int ix0 = (int)fx;
            const float w00 = (1.f - ay) * (1.f - ax);
            const float w01 = (1.f - ay) * ax;
            const float w10 = ay * (1.f - ax);
            const float w11 = ay * ax;
            float vx = 0.f, vy = 0.f;
            const bool x0ok = (unsigned)ix0 < (unsigned)Wn;
            const bool x1ok = (unsigned)(ix0 + 1) < (unsigned)Wn;
            const float* r0 = xc + (ptrdiff_t)iy0 * (Wn * Cn);
            if ((unsigned)iy0 < (unsigned)Hn) {
                if (x0ok) { const float2 t = *reinterpret_cast<const float2*>(r0 + ix0 * Cn);
                            vx = fmaf(w00, t.x, vx); vy = fmaf(w00, t.y, vy); }
                if (x1ok) { const float2 t = *reinterpret_cast<const float2*>(r0 + ix0 * Cn + Cn);
                            vx = fmaf(w01, t.x, vx); vy = fmaf(w01, t.y, vy); }
            }
            if ((unsigned)(iy0 + 1) < (unsigned)Hn) {
                const float* r1 = r0 + Wn * Cn;
                if (x0ok) { const float2 t = *reinterpret_cast<const float2*>(r1 + ix0 * Cn);
                            vx = fmaf(w10, t.x, vx); vy = fmaf(w10, t.y, vy); }
                if (x1ok) { const float2 t = *reinterpret_cast<const float2*>(r1 + ix0 * Cn + Cn);
                            vx = fmaf(w11, t.x, vx); vy = fmaf(w11, t.y, vy); }
            }
            Bld[dbase + k * 32] = pack2bf(vx, vy);
        }
    }
    __syncthreads();

    // ---- Phase 2: out = w_def . sampled via MFMA ----
    v4f acc0 = {0.f,0.f,0.f,0.f};
    const unsigned short* arow = aswz + (size_t)wid * 9216 + lane * 8;
#pragma unroll
    for (int s = 0; s < 18; ++s) {
        const v8s a = *reinterpret_cast<const v8s*>(arow + s * 512);
        const int kb = 32 * s + 4 * g;
        const unsigned short* b0p = &Bl[c15 * RS + kb];
        const v4s lo0 = *reinterpret_cast<const v4s*>(b0p);
        const v4s hi0 = *reinterpret_cast<const v4s*>(b0p + 16);
        const v8s bb0 = {lo0[0],lo0[1],lo0[2],lo0[3],hi0[0],hi0[1],hi0[2],hi0[3]};
        acc0 = __builtin_amdgcn_mfma_f32_16x16x32_bf16(a, bb0, acc0, 0, 0, 0);
    }
    const int co = (wid << 4) + (g << 2);
    float* op = out + ((size_t)(b * COn + co)) * HWn + p0 + c15;
#pragma unroll
    for (int r = 0; r < 4; ++r)
        op[(size_t)r * HWn] = acc0[r];
}

extern "C" void kernel_launch(void* const* d_in, const int* in_sizes, int n_in,
                              void* d_out, int out_size, void* d_ws, size_t ws_size,
                              hipStream_t stream) {
    const float* x     = (const float*)d_in[0];
    const float* w_off = (const float*)d_in[1];
    const float* b_off = (const float*)d_in[2];
    const float* w_def = (const float*)d_in[3];
    float* outp = (float*)d_out;
    float* wsf  = (float*)d_ws;
    float* xt   = wsf + XT_OFF;
    unsigned short* aswz = (unsigned short*)(wsf + ASWZ_OFF);
    unsigned short* aoff = (unsigned short*)(wsf + AOFF_OFF);

    k_transpose<<<Bn * 256, 256, 0, stream>>>(x, xt);
    k_prep<<<216, 256, 0, stream>>>(w_def, w_off, aswz, aoff);
    k_deform<<<Bn * (HWn / TILE), 256, 0, stream>>>(xt, aoff, b_off, aswz, outp);
}

// Round 6
// 65.709 us; speedup vs baseline: 7.7332x; 1.3704x over previous
//
#include <hip/hip_runtime.h>
#include <math.h>

// Deformable conv fwd: B=4, C=CO=64, H=W=128, K=3, pad=1, stride=1.
// ws layout (float units):
//   [0, 4194304)              xt: x transposed to NHWC (16 MiB)
//   [4194304, 4212736)        aswz: w_def bf16 A-frags (72 KiB)
//   [4212736, 4221952)        aoff: w_off bf16 A-frags, rows padded to 32 (36 KiB)
// Panel k-order is TAP-MAJOR: ck' = tap*64 + c  (A-swizzle matches).

typedef short  v4s __attribute__((ext_vector_type(4)));
typedef short  v8s __attribute__((ext_vector_type(8)));
typedef float  v4f __attribute__((ext_vector_type(4)));

namespace {
constexpr int Bn = 4, Cn = 64, Hn = 128, Wn = 128, COn = 64;
constexpr int HWn = 16384;
constexpr int CKn = 576;
constexpr int TILE = 16;                // pixels per block
constexpr int RS = 580;                 // shorts per panel row = 290 dwords (≡2 mod 32)
constexpr size_t XT_OFF   = 0;
constexpr size_t ASWZ_OFF = (size_t)Bn * HWn * Cn;   // float index 4194304
constexpr size_t AOFF_OFF = ASWZ_OFF + 18432;
}

__device__ __forceinline__ unsigned short f2bf(float f) {
    union { float f; unsigned int u; } v; v.f = f;
    unsigned int u = v.u;
    u += 0x7fffu + ((u >> 16) & 1u);    // RNE
    return (unsigned short)(u >> 16);
}
__device__ __forceinline__ unsigned int pack2bf(float a, float b) {
    return (unsigned int)f2bf(a) | ((unsigned int)f2bf(b) << 16);
}

// ---- Kernel 1: NCHW -> NHWC transpose of x ----
__global__ __launch_bounds__(256) void k_transpose(const float* __restrict__ x,
                                                   float* __restrict__ xt) {
    __shared__ float tile[64][65];
    const int tid  = threadIdx.x;
    const int lane = tid & 63;
    const int grp  = tid >> 6;
    const int b    = blockIdx.x >> 8;
    const int hw0  = (blockIdx.x & 255) << 6;
#pragma unroll
    for (int r = 0; r < 16; ++r) {
        const int c = (r << 2) + grp;
        tile[c][lane] = x[(b * Cn + c) * HWn + hw0 + lane];
    }
    __syncthreads();
#pragma unroll
    for (int r = 0; r < 16; ++r) {
        const int hwl = (r << 2) + grp;
        xt[(size_t)(b * HWn + hw0 + hwl) * Cn + lane] = tile[lane][hwl];
    }
}

// ---- Kernel 2: weight swizzle to MFMA A-frag layout, tap-major k ----
// lane l holds A[row=16r+(l&15)][k = 32s+4(l>>4)+(j&3)+16(j>>2)], ck' = tap*64+c
__global__ __launch_bounds__(256) void k_prep(const float* __restrict__ w_def,
                                              const float* __restrict__ w_off,
                                              unsigned short* __restrict__ aswz,
                                              unsigned short* __restrict__ aoff) {
    const int idx = blockIdx.x * 256 + threadIdx.x;   // [0, 36864+18432)
    if (idx < 36864) {
        const int j = idx & 7;
        const int l = (idx >> 3) & 63;
        const int s = (idx >> 9) % 18;
        const int r = idx / 9216;
        const int co = 16 * r + (l & 15);
        const int kk = 32 * s + 4 * (l >> 4) + (j & 3) + 16 * (j >> 2);
        const int tap = kk >> 6, c = kk & 63;
        aswz[idx] = f2bf(w_def[co * CKn + c * 9 + tap]);
    } else {
        const int i2 = idx - 36864;
        const int j = i2 & 7;
        const int l = (i2 >> 3) & 63;
        const int s = (i2 >> 9) % 18;
        const int r = i2 / 9216;
        const int co = 16 * r + (l & 15);
        const int kk = 32 * s + 4 * (l >> 4) + (j & 3) + 16 * (j >> 2);
        const int tap = kk >> 6, c = kk & 63;
        aoff[i2] = (co < 18) ? f2bf(w_off[co * CKn + c * 9 + tap]) : (unsigned short)0;
    }
}

// ---- Kernel 3: fused offset MFMA + bilinear gather + output MFMA ----
__global__ __launch_bounds__(256, 6) void k_deform(const float* __restrict__ xt,
                                                   const unsigned short* __restrict__ aoff,
                                                   const float* __restrict__ b_off,
                                                   const unsigned short* __restrict__ aswz,
                                                   float* __restrict__ out) {
    __shared__ unsigned short Bl[TILE * RS];   // 18560 B panel (tap-major)
    __shared__ float part[4][18][16];          // 4608 B offset partials
    __shared__ float offl[18][16];             // 1152 B offsets
    uint2* Bl2 = (uint2*)Bl;
    const int tid  = threadIdx.x;
    const int lane = tid & 63;
    const int wid  = tid >> 6;
    const int g    = lane >> 4;
    const int c15  = lane & 15;
    const int q    = lane & 15;     // channel-quad
    const int pq   = lane >> 4;     // pixel within wave's 4-px group
    const int b    = blockIdx.x >> 10;           // 1024 tiles per batch
    const int p0   = (blockIdx.x & 1023) * TILE; // 16 consecutive pixels (same row)
    const int pix  = (wid << 2) + pq;            // this lane's pixel (gather phases)
    const int p    = p0 + pix;
    const int oy   = p >> 7;
    const int ox   = p & (Wn - 1);
    const float* xc = xt + (size_t)(b * HWn) * Cn + 4 * q;  // float4 channel base

    // ---- Phase 0a: regular-grid im2col panel (tap-major, float4, 4 px/instr) ----
#pragma unroll
    for (int k = 0; k < 9; ++k) {
        const int sy = oy + k / 3 - 1;
        const int sx = ox + k % 3 - 1;
        float4 t = {0.f, 0.f, 0.f, 0.f};
        if ((unsigned)sy < (unsigned)Hn && (unsigned)sx < (unsigned)Wn)
            t = *reinterpret_cast<const float4*>(xc + (size_t)(sy * Wn + sx) * Cn);
        Bl2[pix * 145 + k * 16 + q] = make_uint2(pack2bf(t.x, t.y), pack2bf(t.z, t.w));
    }
    __syncthreads();

    // ---- Phase 0b: off = w_off . P via MFMA, k-split across waves ----
    {
        v4f pa00 = {0.f,0.f,0.f,0.f};
        v4f pa10 = {0.f,0.f,0.f,0.f};
        for (int s = wid; s < 18; s += 4) {
            const int kb = 32 * s + 4 * g;
            const unsigned short* b0p = &Bl[c15 * RS + kb];
            const v4s lo0 = *reinterpret_cast<const v4s*>(b0p);
            const v4s hi0 = *reinterpret_cast<const v4s*>(b0p + 16);
            const v8s bb0 = {lo0[0],lo0[1],lo0[2],lo0[3],hi0[0],hi0[1],hi0[2],hi0[3]};
            const v8s a0 = *reinterpret_cast<const v8s*>(aoff + (size_t)(0 * 18 + s) * 512 + lane * 8);
            const v8s a1 = *reinterpret_cast<const v8s*>(aoff + (size_t)(1 * 18 + s) * 512 + lane * 8);
            pa00 = __builtin_amdgcn_mfma_f32_16x16x32_bf16(a0, bb0, pa00, 0, 0, 0);
            pa10 = __builtin_amdgcn_mfma_f32_16x16x32_bf16(a1, bb0, pa10, 0, 0, 0);
        }
#pragma unroll
        for (int r = 0; r < 4; ++r) {
            const int co0 = (g << 2) + r;
            part[wid][co0][c15] = pa00[r];
            const int co1 = 16 + (g << 2) + r;
            if (co1 < 18)
                part[wid][co1][c15] = pa10[r];
        }
    }
    __syncthreads();
    for (int idx = tid; idx < 288; idx += 256) {
        const int ch = idx >> 4, px = idx & 15;
        offl[ch][px] = part[0][ch][px] + part[1][ch][px] + part[2][ch][px]
                     + part[3][ch][px] + b_off[ch];
    }
    __syncthreads();

    // ---- Phase 1: bilinear gather -> panel (overwrites Bl; float4, 4 px/instr) ----
#pragma unroll
    for (int k = 0; k < 9; ++k) {
        const float py = offl[2 * k][pix]     + (float)(oy + k / 3 - 1);
        const float px = offl[2 * k + 1][pix] + (float)(ox + k % 3 - 1);
        const float fy = floorf(py);
        const float fx = floorf(px);
        const float ay = py - fy;
        const float ax = px - fx;
        const int iy0 = (int)fy;
        const int ix0 = (int)fx;
        const float w00 = (1.f - ay) * (1.f - ax);
        const float w01 = (1.f - ay) * ax;
        const float w10 = ay * (1.f - ax);
        const float w11 = ay * ax;
        float4 v = {0.f, 0.f, 0.f, 0.f};
        const bool x0ok = (unsigned)ix0 < (unsigned)Wn;
        const bool x1ok = (unsigned)(ix0 + 1) < (unsigned)Wn;
        const float* r0 = xc + (ptrdiff_t)iy0 * (Wn * Cn);
        if ((unsigned)iy0 < (unsigned)Hn) {
            if (x0ok) { const float4 t = *reinterpret_cast<const float4*>(r0 + ix0 * Cn);
                        v.x = fmaf(w00, t.x, v.x); v.y = fmaf(w00, t.y, v.y);
                        v.z = fmaf(w00, t.z, v.z); v.w = fmaf(w00, t.w, v.w); }
            if (x1ok) { const float4 t = *reinterpret_cast<const float4*>(r0 + ix0 * Cn + Cn);
                        v.x = fmaf(w01, t.x, v.x); v.y = fmaf(w01, t.y, v.y);
                        v.z = fmaf(w01, t.z, v.z); v.w = fmaf(w01, t.w, v.w); }
        }
        if ((unsigned)(iy0 + 1) < (unsigned)Hn) {
            const float* r1 = r0 + Wn * Cn;
            if (x0ok) { const float4 t = *reinterpret_cast<const float4*>(r1 + ix0 * Cn);
                        v.x = fmaf(w10, t.x, v.x); v.y = fmaf(w10, t.y, v.y);
                        v.z = fmaf(w10, t.z, v.z); v.w = fmaf(w10, t.w, v.w); }
            if (x1ok) { const float4 t = *reinterpret_cast<const float4*>(r1 + ix0 * Cn + Cn);
                        v.x = fmaf(w11, t.x, v.x); v.y = fmaf(w11, t.y, v.y);
                        v.z = fmaf(w11, t.z, v.z); v.w = fmaf(w11, t.w, v.w); }
        }
        Bl2[pix * 145 + k * 16 + q] = make_uint2(pack2bf(v.x, v.y), pack2bf(v.z, v.w));
    }
    __syncthreads();

    // ---- Phase 2: out = w_def . sampled via MFMA ----
    v4f acc0 = {0.f,0.f,0.f,0.f};
    const unsigned short* arow = aswz + (size_t)wid * 9216 + lane * 8;
#pragma unroll
    for (int s = 0; s < 18; ++s) {
        const v8s a = *reinterpret_cast<const v8s*>(arow + s * 512);
        const int kb = 32 * s + 4 * g;
        const unsigned short* b0p = &Bl[c15 * RS + kb];
        const v4s lo0 = *reinterpret_cast<const v4s*>(b0p);
        const v4s hi0 = *reinterpret_cast<const v4s*>(b0p + 16);
        const v8s bb0 = {lo0[0],lo0[1],lo0[2],lo0[3],hi0[0],hi0[1],hi0[2],hi0[3]};
        acc0 = __builtin_amdgcn_mfma_f32_16x16x32_bf16(a, bb0, acc0, 0, 0, 0);
    }
    const int co = (wid << 4) + (g << 2);
    float* op = out + ((size_t)(b * COn + co)) * HWn + p0 + c15;
#pragma unroll
    for (int r = 0; r < 4; ++r)
        op[(size_t)r * HWn] = acc0[r];
}

extern "C" void kernel_launch(void* const* d_in, const int* in_sizes, int n_in,
                              void* d_out, int out_size, void* d_ws, size_t ws_size,
                              hipStream_t stream) {
    const float* x     = (const float*)d_in[0];
    const float* w_off = (const float*)d_in[1];
    const float* b_off = (const float*)d_in[2];
    const float* w_def = (const float*)d_in[3];
    float* outp = (float*)d_out;
    float* wsf  = (float*)d_ws;
    float* xt   = wsf + XT_OFF;
    unsigned short* aswz = (unsigned short*)(wsf + ASWZ_OFF);
    unsigned short* aoff = (unsigned short*)(wsf + AOFF_OFF);

    k_transpose<<<Bn * 256, 256, 0, stream>>>(x, xt);
    k_prep<<<216, 256, 0, stream>>>(w_def, w_off, aswz, aoff);
    k_deform<<<Bn * (HWn / TILE), 256, 0, stream>>>(xt, aoff, b_off, aswz, outp);
}

// Round 7
// 56.207 us; speedup vs baseline: 9.0406x; 1.1691x over previous
//
#include <hip/hip_runtime.h>
#include <math.h>

// Deformable conv fwd: B=4, C=CO=64, H=W=128, K=3, pad=1, stride=1.
// ws layout (float units):
//   [0, 2230272)              xh: x as bf16 NHWC with 2-px zero halo
//                                 [B][132][132][64] bf16 (8.92 MiB)
//   [2230272, 2248704)        aswz: w_def bf16 A-frags (72 KiB)
//   [2248704, 2257920)        aoff: w_off bf16 A-frags, rows padded to 32 (36 KiB)
// Panel k-order is TAP-MAJOR: ck' = tap*64 + c  (A-swizzle matches).

typedef short  v4s __attribute__((ext_vector_type(4)));
typedef short  v8s __attribute__((ext_vector_type(8)));
typedef float  v4f __attribute__((ext_vector_type(4)));
typedef float  v2f __attribute__((ext_vector_type(2)));

namespace {
constexpr int Bn = 4, Cn = 64, Hn = 128, Wn = 128, COn = 64;
constexpr int HWn = 16384;
constexpr int CKn = 576;
constexpr int TILE = 16;                // pixels per block
constexpr int RS = 580;                 // shorts per panel row = 290 dwords (≡2 mod 32)
constexpr int HW2 = 132;                // haloed width
constexpr int XPITCH = HW2 * 16;        // uint2 per halo row (132 px * 16 uint2)
constexpr size_t XH_OFF   = 0;
constexpr size_t ASWZ_OFF = 2230272;    // floats: 4*132*132*64 bf16 / 2
constexpr size_t AOFF_OFF = ASWZ_OFF + 18432;
}

__device__ __forceinline__ unsigned short f2bf(float f) {
    union { float f; unsigned int u; } v; v.f = f;
    unsigned int u = v.u;
    u += 0x7fffu + ((u >> 16) & 1u);    // RNE
    return (unsigned short)(u >> 16);
}
__device__ __forceinline__ unsigned int pack2bf(float a, float b) {
    return (unsigned int)f2bf(a) | ((unsigned int)f2bf(b) << 16);
}
__device__ __forceinline__ v2f unpk(unsigned int u) {
    v2f r;
    r.x = __uint_as_float(u << 16);
    r.y = __uint_as_float(u & 0xffff0000u);
    return r;
}

// ---- Kernel 1: NCHW fp32 -> bf16 NHWC halo buffer ----
__global__ __launch_bounds__(256) void k_halo(const float* __restrict__ x,
                                              unsigned int* __restrict__ xh) {
    __shared__ float tile[64][65];
    const int tid  = threadIdx.x;
    const int lane = tid & 63;
    const int grp  = tid >> 6;
    const int b    = blockIdx.x >> 8;
    const int hw0  = (blockIdx.x & 255) << 6;
#pragma unroll
    for (int r = 0; r < 16; ++r) {
        const int c = (r << 2) + grp;
        tile[c][lane] = x[(b * Cn + c) * HWn + hw0 + lane];
    }
    __syncthreads();
    const int h = lane >> 5;
    const int m = lane & 31;
#pragma unroll
    for (int r = 0; r < 8; ++r) {
        const int hwl = (r << 3) + (grp << 1) + h;   // 0..63
        const int hw  = hw0 + hwl;
        const int yy  = hw >> 7;
        const int xx  = hw & (Wn - 1);
        const unsigned int u = pack2bf(tile[2 * m][hwl], tile[2 * m + 1][hwl]);
        xh[((size_t)(b * HW2 + yy + 2) * HW2 + (xx + 2)) * 32 + m] = u;
    }
}

// ---- Kernel 2: weight swizzle to MFMA A-frag layout, tap-major k ----
// lane l holds A[row=16r+(l&15)][k = 32s+4(l>>4)+(j&3)+16(j>>2)], ck' = tap*64+c
__global__ __launch_bounds__(256) void k_prep(const float* __restrict__ w_def,
                                              const float* __restrict__ w_off,
                                              unsigned short* __restrict__ aswz,
                                              unsigned short* __restrict__ aoff) {
    const int idx = blockIdx.x * 256 + threadIdx.x;   // [0, 36864+18432)
    if (idx < 36864) {
        const int j = idx & 7;
        const int l = (idx >> 3) & 63;
        const int s = (idx >> 9) % 18;
        const int r = idx / 9216;
        const int co = 16 * r + (l & 15);
        const int kk = 32 * s + 4 * (l >> 4) + (j & 3) + 16 * (j >> 2);
        const int tap = kk >> 6, c = kk & 63;
        aswz[idx] = f2bf(w_def[co * CKn + c * 9 + tap]);
    } else {
        const int i2 = idx - 36864;
        const int j = i2 & 7;
        const int l = (i2 >> 3) & 63;
        const int s = (i2 >> 9) % 18;
        const int r = i2 / 9216;
        const int co = 16 * r + (l & 15);
        const int kk = 32 * s + 4 * (l >> 4) + (j & 3) + 16 * (j >> 2);
        const int tap = kk >> 6, c = kk & 63;
        aoff[i2] = (co < 18) ? f2bf(w_off[co * CKn + c * 9 + tap]) : (unsigned short)0;
    }
}

// ---- Kernel 3: fused offset MFMA + bilinear gather + output MFMA ----
__global__ __launch_bounds__(256, 6) void k_deform(const uint2* __restrict__ xh2,
                                                   const unsigned short* __restrict__ aoff,
                                                   const float* __restrict__ b_off,
                                                   const unsigned short* __restrict__ aswz,
                                                   float* __restrict__ out) {
    __shared__ unsigned short Bl[TILE * RS];   // 18560 B panel (tap-major)
    __shared__ float part[4][18][16];          // 4608 B offset partials
    __shared__ float offl[18][16];             // 1152 B offsets
    uint2* Bl2 = (uint2*)Bl;
    const int tid  = threadIdx.x;
    const int lane = tid & 63;
    const int wid  = tid >> 6;
    const int g    = lane >> 4;
    const int c15  = lane & 15;
    const int q    = lane & 15;     // channel-quad
    const int pq   = lane >> 4;     // pixel within wave's 4-px group
    const int b    = blockIdx.x >> 10;           // 1024 tiles per batch
    const int p0   = (blockIdx.x & 1023) * TILE; // 16 consecutive pixels (same row)
    const int pix  = (wid << 2) + pq;            // this lane's pixel (gather phases)
    const int p    = p0 + pix;
    const int oy   = p >> 7;
    const int ox   = p & (Wn - 1);
    const int xbase = b * (HW2 * HW2 * 16);      // uint2 units

    // ---- Phase 0a: regular-grid im2col panel (pure bf16 copy, in-bounds by halo) ----
#pragma unroll
    for (int k = 0; k < 9; ++k) {
        const int sy = oy + k / 3 - 1;           // in [-1,128] ⊂ halo
        const int sx = ox + k % 3 - 1;
        const uint2 t = xh2[xbase + ((sy + 2) * HW2 + (sx + 2)) * 16 + q];
        Bl2[pix * 145 + k * 16 + q] = t;
    }
    __syncthreads();

    // ---- Phase 0b: off = w_off . P via MFMA, k-split across waves ----
    {
        v4f pa00 = {0.f,0.f,0.f,0.f};
        v4f pa10 = {0.f,0.f,0.f,0.f};
        for (int s = wid; s < 18; s += 4) {
            const int kb = 32 * s + 4 * g;
            const unsigned short* b0p = &Bl[c15 * RS + kb];
            const v4s lo0 = *reinterpret_cast<const v4s*>(b0p);
            const v4s hi0 = *reinterpret_cast<const v4s*>(b0p + 16);
            const v8s bb0 = {lo0[0],lo0[1],lo0[2],lo0[3],hi0[0],hi0[1],hi0[2],hi0[3]};
            const v8s a0 = *reinterpret_cast<const v8s*>(aoff + (size_t)(0 * 18 + s) * 512 + lane * 8);
            const v8s a1 = *reinterpret_cast<const v8s*>(aoff + (size_t)(1 * 18 + s) * 512 + lane * 8);
            pa00 = __builtin_amdgcn_mfma_f32_16x16x32_bf16(a0, bb0, pa00, 0, 0, 0);
            pa10 = __builtin_amdgcn_mfma_f32_16x16x32_bf16(a1, bb0, pa10, 0, 0, 0);
        }
#pragma unroll
        for (int r = 0; r < 4; ++r) {
            const int co0 = (g << 2) + r;
            part[wid][co0][c15] = pa00[r];
            const int co1 = 16 + (g << 2) + r;
            if (co1 < 18)
                part[wid][co1][c15] = pa10[r];
        }
    }
    __syncthreads();
    for (int idx = tid; idx < 288; idx += 256) {
        const int ch = idx >> 4, px = idx & 15;
        offl[ch][px] = part[0][ch][px] + part[1][ch][px] + part[2][ch][px]
                     + part[3][ch][px] + b_off[ch];
    }
    __syncthreads();

    // ---- Phase 1: bilinear gather, branch-free via halo+clamp ----
#pragma unroll
    for (int k = 0; k < 9; ++k) {
        const float py = offl[2 * k][pix]     + (float)(oy + k / 3 - 1);
        const float px = offl[2 * k + 1][pix] + (float)(ox + k % 3 - 1);
        const float fy = floorf(py);
        const float fx = floorf(px);
        const float ay = py - fy;               // in [0,1) always
        const float ax = px - fx;
        int iy0 = (int)fy;
        int ix0 = (int)fx;
        iy0 = max(-2, min(iy0, 128));           // clamped corners read halo zeros
        ix0 = max(-2, min(ix0, 128));
        const float w00 = (1.f - ay) * (1.f - ax);
        const float w01 = (1.f - ay) * ax;
        const float w10 = ay * (1.f - ax);
        const float w11 = ay * ax;
        const uint2* r0 = xh2 + xbase + ((iy0 + 2) * HW2 + (ix0 + 2)) * 16 + q;
        const uint2 u00 = r0[0];
        const uint2 u01 = r0[16];
        const uint2 u10 = r0[XPITCH];
        const uint2 u11 = r0[XPITCH + 16];
        v2f va = unpk(u00.x) * w00;
        va += unpk(u01.x) * w01;
        va += unpk(u10.x) * w10;
        va += unpk(u11.x) * w11;
        v2f vb = unpk(u00.y) * w00;
        vb += unpk(u01.y) * w01;
        vb += unpk(u10.y) * w10;
        vb += unpk(u11.y) * w11;
        Bl2[pix * 145 + k * 16 + q] = make_uint2(pack2bf(va.x, va.y), pack2bf(vb.x, vb.y));
    }
    __syncthreads();

    // ---- Phase 2: out = w_def . sampled via MFMA ----
    v4f acc0 = {0.f,0.f,0.f,0.f};
    const unsigned short* arow = aswz + (size_t)wid * 9216 + lane * 8;
#pragma unroll
    for (int s = 0; s < 18; ++s) {
        const v8s a = *reinterpret_cast<const v8s*>(arow + s * 512);
        const int kb = 32 * s + 4 * g;
        const unsigned short* b0p = &Bl[c15 * RS + kb];
        const v4s lo0 = *reinterpret_cast<const v4s*>(b0p);
        const v4s hi0 = *reinterpret_cast<const v4s*>(b0p + 16);
        const v8s bb0 = {lo0[0],lo0[1],lo0[2],lo0[3],hi0[0],hi0[1],hi0[2],hi0[3]};
        acc0 = __builtin_amdgcn_mfma_f32_16x16x32_bf16(a, bb0, acc0, 0, 0, 0);
    }
    const int co = (wid << 4) + (g << 2);
    float* op = out + ((size_t)(b * COn + co)) * HWn + p0 + c15;
#pragma unroll
    for (int r = 0; r < 4; ++r)
        op[(size_t)r * HWn] = acc0[r];
}

extern "C" void kernel_launch(void* const* d_in, const int* in_sizes, int n_in,
                              void* d_out, int out_size, void* d_ws, size_t ws_size,
                              hipStream_t stream) {
    const float* x     = (const float*)d_in[0];
    const float* w_off = (const float*)d_in[1];
    const float* b_off = (const float*)d_in[2];
    const float* w_def = (const float*)d_in[3];
    float* outp = (float*)d_out;
    float* wsf  = (float*)d_ws;
    unsigned int* xh = (unsigned int*)(wsf + XH_OFF);
    unsigned short* aswz = (unsigned short*)(wsf + ASWZ_OFF);
    unsigned short* aoff = (unsigned short*)(wsf + AOFF_OFF);

    // zero the halo buffer (borders must be 0; interior overwritten by k_halo)
    hipMemsetAsync(xh, 0, (size_t)Bn * HW2 * HW2 * Cn * 2, stream);
    k_halo<<<Bn * 256, 256, 0, stream>>>(x, xh);
    k_prep<<<216, 256, 0, stream>>>(w_def, w_off, aswz, aoff);
    k_deform<<<Bn * (HWn / TILE), 256, 0, stream>>>((const uint2*)xh, aoff, b_off, aswz, outp);
}